// Round 2
// baseline (11207.659 us; speedup 1.0000x reference)
//
#include <hip/hip_runtime.h>
#include <hip/hip_bf16.h>

// PointerNet MI355X — Round 12: latency-structured recurrent steps.
// vs R11: (1) batch-major recurrent tensors [64][K] -> u64 coherent loads
// (4/group instead of 8 scalars); (2) explicit depth-3 rolling prefetch over
// K-groups (bounded VGPR, loads provably in flight); (3) grid barrier split
// into arrive/wait with useful work hidden in the window (enc: emb half of
// GEMM; dec: P1 dinT-part in g5 window, P3 initial ctx prefetch in g2 window);
// (4) split8v packs planes with bit-ops (v_perm-fusable), values bit-identical.
// Arithmetic op-identical to R10/R11 (absmax expected 1.525879e-05).

typedef unsigned short u16;
typedef unsigned long long u64;
typedef __bf16 bf16_t;
typedef bf16_t bf16x8 __attribute__((ext_vector_type(8)));
typedef float f32x4 __attribute__((ext_vector_type(4)));

#define MFMA16(a, b, c) __builtin_amdgcn_mfma_f32_16x16x32_bf16(a, b, c, 0, 0, 0)
#define AGENT __HIP_MEMORY_SCOPE_AGENT

// ---------------- ws layout (bytes) ----------------
#define FLG_OFF   64u
#define GENE_OFF  128u
#define LDE_OFF   192u           // 16 x 64B leaf lines (encoder)
#define FLE_OFF   1216u          // 160 x 64B flag lines (encoder)
#define GEND_OFF  11456u
#define LDD_OFF   11520u         // 16 x 64B leaf lines (decoder)
#define FLD_OFF   12544u         // 256 x 64B flag lines (decoder)
#define BAR_END   28928u
#define HE_OFF    32768u         // f32 [2][64][512] enc h ping-pong BATCH-MAJOR
#define CW_OFF    294912u        // f32 [64][512] c hand-off enc->dec
#define HD_OFF    425984u        // f32 [64][512] dec h carry BATCH-MAJOR
#define AO_OFF    557056u        // f32 [64][1024] concat [hidden|h_t] BATCH-MAJOR
#define INP_OFF   819200u        // f32 [64][512]
#define ATT_OFF   950272u        // f32 [64][512]
#define MSK_OFF   1081344u       // f32 [64][512]
#define PAC_OFF   1212416u       // f32 [64][4][512]
#define PML_OFF   1736704u       // f32 [64][4][2]
#define DIN_OFF   1740800u       // f32 [64][256] BATCH-MAJOR
#define CTX_OFF   2097152u       // tier0 f32 64MiB; tier1 bf16+i8
#define CTXL_OFF  (CTX_OFF + 33554432u)
#define NEED_T0   (CTX_OFF + 67108864u)
#define NEED_T1   (CTX_OFF + 50331648u)
#define NEED_T2   (CTX_OFF + 33554432u)

__device__ __forceinline__ float bf2f(u16 b) {
  union { unsigned u; float f; } c; c.u = ((unsigned)b) << 16; return c.f;
}
__device__ __forceinline__ u16 f2bf(float x) {
  union { float f; unsigned u; } c; c.f = x;
  unsigned r = c.u + 0x7FFFu + ((c.u >> 16) & 1u);
  return (u16)(r >> 16);
}
__device__ __forceinline__ float sigf(float x) { return 1.0f / (1.0f + expf(-x)); }
__device__ __forceinline__ float sel4(float a0, float a1, float a2, float a3, int j) {
  float r = (j == 1) ? a1 : a0;
  r = (j == 2) ? a2 : r;
  r = (j == 3) ? a3 : r;
  return r;
}
__device__ __forceinline__ float wget(const void* p, long i, int f32m) {
  return f32m ? ((const float*)p)[i] : bf2f(((const u16*)p)[i]);
}
__device__ __forceinline__ void ld8(const void* p, long i, int f32m, float (&o)[8]) {
  if (f32m) {
    const float4* q = (const float4*)((const float*)p + i);
    float4 a = q[0], b = q[1];
    o[0] = a.x; o[1] = a.y; o[2] = a.z; o[3] = a.w;
    o[4] = b.x; o[5] = b.y; o[6] = b.z; o[7] = b.w;
  } else {
    uint4 u = *(const uint4*)((const u16*)p + i);
    unsigned ww[4] = {u.x, u.y, u.z, u.w};
#pragma unroll
    for (int k = 0; k < 4; ++k) {
      o[2 * k] = bf2f((u16)(ww[k] & 0xFFFFu));
      o[2 * k + 1] = bf2f((u16)(ww[k] >> 16));
    }
  }
}
// relaxed agent-scope atomics (sc0/sc1: write-through + cache-bypass)
__device__ __forceinline__ float ald(const float* p) {
  return __hip_atomic_load(p, __ATOMIC_RELAXED, AGENT);
}
__device__ __forceinline__ void ast(float* p, float v) {
  __hip_atomic_store(p, v, __ATOMIC_RELAXED, AGENT);
}
__device__ __forceinline__ int aldi(const int* p) {
  return __hip_atomic_load(p, __ATOMIC_RELAXED, AGENT);
}
// coherent 8-floats load from a batch-major row: 4 x u64 atomic loads
__device__ __forceinline__ void ld8c(const float* row, int off, float (&o)[8]) {
  const u64* p = (const u64*)(row + off);
#pragma unroll
  for (int j = 0; j < 4; ++j) {
    union { u64 u; float f[2]; } c;
    c.u = __hip_atomic_load(p + j, __ATOMIC_RELAXED, AGENT);
    o[2 * j] = c.f[0]; o[2 * j + 1] = c.f[1];
  }
}

// 3-plane truncation split (scalar form; used for staging + hand-offs)
__device__ __forceinline__ void split3(float x, u16& h, u16& l, u16& l2) {
  union { float f; unsigned u; } c; c.f = x;
  h = (u16)(c.u >> 16);
  float r = x - bf2f(h);
  union { float f; unsigned u; } e; e.f = r;
  l = (u16)(e.u >> 16);
  float r2 = r - bf2f(l);
  union { float f; unsigned u; } g; g.f = r2;
  l2 = (u16)(g.u >> 16);
}
// vector form: identical plane values, packs pairs with bit-ops (perm-fusable)
__device__ __forceinline__ void split8v(const float (&a)[8], bf16x8& H, bf16x8& L,
                                        bf16x8& L2) {
  union { unsigned u[4]; bf16x8 v; } hh, ll, mm;
#pragma unroll
  for (int k = 0; k < 4; ++k) {
    union { float f; unsigned u; } x0, x1;
    x0.f = a[2 * k]; x1.f = a[2 * k + 1];
    unsigned t0 = x0.u & 0xFFFF0000u, t1 = x1.u & 0xFFFF0000u;
    union { unsigned u; float f; } b0, b1; b0.u = t0; b1.u = t1;
    float r0 = x0.f - b0.f, r1 = x1.f - b1.f;
    union { float f; unsigned u; } e0, e1; e0.f = r0; e1.f = r1;
    unsigned s0 = e0.u & 0xFFFF0000u, s1 = e1.u & 0xFFFF0000u;
    union { unsigned u; float f; } c0, c1; c0.u = s0; c1.u = s1;
    float q0 = r0 - c0.f, q1 = r1 - c1.f;
    union { float f; unsigned u; } g0, g1; g0.f = q0; g1.f = q1;
    hh.u[k] = t1 | (x0.u >> 16);
    ll.u[k] = s1 | (e0.u >> 16);
    mm.u[k] = (g1.u & 0xFFFF0000u) | (g0.u >> 16);
  }
  H = hh.v; L = ll.v; L2 = mm.v;
}
__device__ __forceinline__ f32x4 mfma6(const bf16x8& ah, const bf16x8& al,
                                       const bf16x8& al2, const bf16x8& bh,
                                       const bf16x8& bl, const bf16x8& bl2, f32x4 acc) {
  acc = MFMA16(ah, bh, acc);
  acc = MFMA16(al, bh, acc);
  acc = MFMA16(ah, bl, acc);
  acc = MFMA16(al, bl, acc);
  acc = MFMA16(ah, bl2, acc);
  acc = MFMA16(al2, bh, acc);
  return acc;
}
__device__ __forceinline__ f32x4 groupMMv(const float (&a8)[8], const u16* B3c, int bo,
                                          f32x4 acc) {
  bf16x8 H, L, L2;
  split8v(a8, H, L, L2);
  return mfma6(H, L, L2, *(const bf16x8*)(B3c + bo), *(const bf16x8*)(B3c + 4224 + bo),
               *(const bf16x8*)(B3c + 8448 + bo), acc);
}
__device__ __forceinline__ void stage16(u16* B3, const void* W, int f32m,
                                        long src, int n, int k16) {
  float t0[8], t1[8];
  ld8(W, src, f32m, t0);
  ld8(W, src + 8, f32m, t1);
#pragma unroll
  for (int j = 0; j < 8; ++j) {
    u16 h, l, l2; split3(t0[j], h, l, l2);
    int o = n * 264 + k16 + j;
    B3[o] = h; B3[4224 + o] = l; B3[8448 + o] = l2;
  }
#pragma unroll
  for (int j = 0; j < 8; ++j) {
    u16 h, l, l2; split3(t1[j], h, l, l2);
    int o = n * 264 + k16 + 8 + j;
    B3[o] = h; B3[4224 + o] = l; B3[8448 + o] = l2;
  }
}

// ---- ctx codec (cross-kernel hand-off: plain stores/loads) ----
__device__ __forceinline__ void ctx_store(char* ws, int tier, int oi, float x) {
  if (tier == 0) { ((float*)(ws + CTX_OFF))[oi] = x; return; }
  if (tier >= 3) return;
  u16 hi = f2bf(x);
  ((u16*)(ws + CTX_OFF))[oi] = hi;
  if (tier == 1) {
    unsigned e = hi & 0x7F80u; if (e == 0) e = 0x0080u;
    float us = bf2f((u16)e) * 0.00390625f;
    float r = (x - bf2f(hi)) / us;
    int q = (int)__float2int_rn(r * 254.0f);
    q = max(-127, min(127, q));
    ((signed char*)(ws + CTXL_OFF))[oi] = (signed char)q;
  }
}
__device__ __forceinline__ void ctx_load8(const char* ws, int tier, int oi, float (&cx)[8]) {
  if (tier == 0) {
    const float4* p = (const float4*)((const float*)(ws + CTX_OFF) + oi);
    float4 a = p[0], b = p[1];
    cx[0] = a.x; cx[1] = a.y; cx[2] = a.z; cx[3] = a.w;
    cx[4] = b.x; cx[5] = b.y; cx[6] = b.z; cx[7] = b.w;
    return;
  }
  if (tier >= 3) {
#pragma unroll
    for (int j = 0; j < 8; ++j) cx[j] = 0.0f;
    return;
  }
  uint4 hu = *(const uint4*)((const u16*)(ws + CTX_OFF) + oi);
  unsigned hw[4] = {hu.x, hu.y, hu.z, hu.w};
  u16 h[8];
#pragma unroll
  for (int k = 0; k < 4; ++k) { h[2*k] = (u16)(hw[k] & 0xFFFFu); h[2*k+1] = (u16)(hw[k] >> 16); }
#pragma unroll
  for (int j = 0; j < 8; ++j) cx[j] = bf2f(h[j]);
  if (tier == 1) {
    const signed char* lp = (const signed char*)(ws + CTXL_OFF) + oi;
#pragma unroll
    for (int j = 0; j < 8; ++j) {
      unsigned e = h[j] & 0x7F80u; if (e == 0) e = 0x0080u;
      float us = bf2f((u16)e) * 0.00390625f;
      cx[j] += (float)lp[j] * us * (1.0f / 254.0f);
    }
  }
}

// ---- fence-free hierarchical grid barrier, split arrive/wait ----
__device__ __forceinline__ void sbar_arrive(char* ws, unsigned flOff, int wg, int gen) {
  __builtin_amdgcn_s_waitcnt(0);   // payload sc1 stores + loads drained
  __syncthreads();
  if (threadIdx.x == 0)
    __hip_atomic_store((int*)(ws + flOff) + wg * 16, gen, __ATOMIC_RELAXED, AGENT);
}
__device__ __forceinline__ void sbar_wait(char* ws, unsigned flOff, unsigned ldOff,
                                          unsigned genOff, int wg, int nwg, int gen) {
  const int tid = threadIdx.x;
  if (tid < 64) {
    int* fl = (int*)(ws + flOff);
    int* ldv = (int*)(ws + ldOff);
    int* gp = (int*)(ws + genOff);
    const int mem = nwg >> 4;
    if (wg < 16) {
      if (tid < mem) {
        const int* f = &fl[(wg + (tid << 4)) * 16];
        while (aldi(f) < gen) __builtin_amdgcn_s_sleep(2);
      }
      if (tid == 0) __hip_atomic_store(&ldv[wg * 16], gen, __ATOMIC_RELAXED, AGENT);
    }
    if (wg == 0) {
      if (tid < 16) {
        const int* f = &ldv[tid * 16];
        while (aldi(f) < gen) __builtin_amdgcn_s_sleep(2);
      }
      if (tid == 0) __hip_atomic_store(gp, gen, __ATOMIC_RELAXED, AGENT);
    }
    if (tid == 0)
      while (aldi((const int*)gp) < gen) __builtin_amdgcn_s_sleep(2);
  }
  __syncthreads();
}

// =================== prep ===================
__global__ void prep_detect(const void* embE, char* ws) {
  __shared__ int cnt;
  if (threadIdx.x == 0) cnt = 0;
  __syncthreads();
  const u16* p = (const u16*)embE;
  int c = 0;
  for (int i = threadIdx.x; i < 4096; i += 256) {
    float v = bf2f(p[i]);
    if (!(fabsf(v) < 4.0f)) c++;
  }
  atomicAdd(&cnt, c);
  __syncthreads();
  if (threadIdx.x == 0) *(int*)(ws + FLG_OFF) = (cnt > 200) ? 1 : 0;
}

__global__ void prep_init(const void* din0, char* ws) {
  const int f32m = *(const int*)(ws + FLG_OFF);
  int i0 = blockIdx.x * 256 + threadIdx.x;
  int stride = gridDim.x * 256;
  int* bars = (int*)ws;
  for (int i = i0; i < (int)((BAR_END - GENE_OFF) / 4); i += stride)
    bars[(GENE_OFF / 4) + i] = 0;
  float* h0 = (float*)(ws + HE_OFF);             // slot 0 only
  float* mask = (float*)(ws + MSK_OFF);
  float* dinT = (float*)(ws + DIN_OFF);          // [64][256]
  for (int i = i0; i < 32768; i += stride) { h0[i] = 0.0f; mask[i] = 1.0f; }
  for (int i = i0; i < 16384; i += stride) dinT[i] = wget(din0, i & 255, f32m);
}

// =================== persistent encoder ===================
// grid 160 x 256. WGs 0..127: gates (weights LDS-stationary, c in regs).
// WGs 128..159: ctx row t-1. h ping-pong [2][64][512] batch-major. Per step:
// emb half of GEMM computed in the arrive->wait window (independent of
// h_{t-1}); h half via depth-3 rolling u64 prefetch.
__global__ __launch_bounds__(256, 1) void enc_pers(
    const int* __restrict__ sent, const void* __restrict__ embE,
    const void* __restrict__ Wih, const void* __restrict__ Whh,
    const void* __restrict__ bih, const void* __restrict__ bhh,
    const void* __restrict__ Wctx, const void* __restrict__ bctx,
    char* __restrict__ ws, int tier) {
  __shared__ __align__(16) u16 B3[38016];        // 3 chunks x 12672
  const int tid = threadIdx.x, w = blockIdx.x;
  const int f32m = *(const int*)(ws + FLG_OFF);
  const int lane = tid & 63, v = tid >> 6, ln15 = lane & 15, q = lane >> 4;
  const int bA = v * 16 + ln15;
  const int sn = tid >> 4, sk = (tid & 15) * 16;
  float* heT = (float*)(ws + HE_OFF);
  float* cwp = (float*)(ws + CW_OFF);

  const int g = ln15 & 3;
  const int unit = w * 4 + (ln15 >> 2);        // gate WGs only
  float creg[4];
#pragma unroll
  for (int r = 0; r < 4; ++r) creg[r] = 0.0f;
  float bias = 0.0f;

  // ---- stage all weight chunks ONCE (loop-invariant) ----
  if (w < 128) {
    long grC = (long)(g * 512 + unit);
    bias = wget(bih, grC, f32m) + wget(bhh, grC, f32m);
    const long grS = (long)((sn & 3) * 512 + w * 4 + (sn >> 2));
    stage16(B3, Wih, f32m, grS * 256 + sk, sn, sk);
    stage16(B3 + 12672, Whh, f32m, grS * 512 + sk, sn, sk);
    stage16(B3 + 25344, Whh, f32m, grS * 512 + 256 + sk, sn, sk);
  } else {
    const long grS = (long)((w - 128) * 16 + sn);
    stage16(B3, Wctx, f32m, grS * 512 + sk, sn, sk);
    stage16(B3 + 12672, Wctx, f32m, grS * 512 + 256 + sk, sn, sk);
  }
  __syncthreads();

#pragma unroll 1
  for (int t = 0; t < 512; ++t) {
    const int slot = t & 1;
    if (w < 128) {
      // ---- emb half: independent of h_{t-1}; overlaps barrier wait ----
      const int tok = sent[t * 64 + bA];
      f32x4 acc = {0.f, 0.f, 0.f, 0.f};
      {
        float aE[4][8];
#pragma unroll
        for (int pf = 0; pf < 3; ++pf)
          ld8(embE, (long)tok * 256 + pf * 32 + q * 8, f32m, aE[pf]);
#pragma unroll
        for (int ks = 0; ks < 8; ++ks) {
          if (ks + 3 < 8) ld8(embE, (long)tok * 256 + (ks + 3) * 32 + q * 8, f32m,
                              aE[(ks + 3) & 3]);
          acc = groupMMv(aE[ks & 3], B3, ln15 * 264 + ks * 32 + q * 8, acc);
        }
      }
      if (t) sbar_wait(ws, FLE_OFF, LDE_OFF, GENE_OFF, w, 160, t);
      // ---- h half: depth-3 rolling prefetch ----
      {
        const float* hrow = heT + slot * 32768 + bA * 512;
        float aH[4][8];
#pragma unroll
        for (int pf = 0; pf < 3; ++pf) ld8c(hrow, pf * 32 + q * 8, aH[pf]);
#pragma unroll
        for (int kk = 0; kk < 16; ++kk) {
          if (kk + 3 < 16) ld8c(hrow, (kk + 3) * 32 + q * 8, aH[(kk + 3) & 3]);
          acc = groupMMv(aH[kk & 3], B3 + (1 + (kk >> 3)) * 12672,
                         ln15 * 264 + (kk & 7) * 32 + q * 8, acc);
        }
      }
      float* hdTs = heT + (slot ^ 1) * 32768;
#pragma unroll
      for (int r = 0; r < 4; ++r) {
        int br = v * 16 + q * 4 + r;
        float val = acc[r] + bias;
        float x1 = __shfl_xor(val, 1);
        float x2 = __shfl_xor(val, 2);
        float x3 = __shfl_xor(val, 3);
        float gi = sel4(val, x1, x2, x3, g);
        float gf = sel4(val, x1, x2, x3, g ^ 1);
        float gg = sel4(val, x1, x2, x3, g ^ 2);
        float go = sel4(val, x1, x2, x3, g ^ 3);
        float cn = sigf(gf) * creg[r] + sigf(gi) * tanhf(gg);
        float hv = sigf(go) * tanhf(cn);
        creg[r] = cn;                        // all quad lanes track identical c
        if (g == 0) ast(hdTs + br * 512 + unit, hv);
      }
    } else {
      if (t) {
        sbar_wait(ws, FLE_OFF, LDE_OFF, GENE_OFF, w, 160, t);
        const float* hrow = heT + slot * 32768 + bA * 512;
        float aH[4][8];
#pragma unroll
        for (int pf = 0; pf < 3; ++pf) ld8c(hrow, pf * 32 + q * 8, aH[pf]);
        f32x4 acc = {0.f, 0.f, 0.f, 0.f};
#pragma unroll
        for (int kk = 0; kk < 16; ++kk) {
          if (kk + 3 < 16) ld8c(hrow, (kk + 3) * 32 + q * 8, aH[(kk + 3) & 3]);
          acc = groupMMv(aH[kk & 3], B3 + (kk >> 3) * 12672,
                         ln15 * 264 + (kk & 7) * 32 + q * 8, acc);
        }
        const int d = (w - 128) * 16 + ln15;
        float bb = wget(bctx, d, f32m);
#pragma unroll
        for (int r = 0; r < 4; ++r) {
          int br = v * 16 + q * 4 + r;
          ctx_store(ws, tier, (br * 512 + (t - 1)) * 512 + d, acc[r] + bb);
        }
      }
    }
    sbar_arrive(ws, FLE_OFF, w, t + 1);
  }
  // tail: everyone waits gen 512 (leaders must propagate for the ctx tail)
  sbar_wait(ws, FLE_OFF, LDE_OFF, GENE_OFF, w, 160, 512);
  if (w >= 128) {
    // ctx row 511 from h_511 (slot 0)
    const float* hrow = heT + bA * 512;
    float aH[4][8];
#pragma unroll
    for (int pf = 0; pf < 3; ++pf) ld8c(hrow, pf * 32 + q * 8, aH[pf]);
    f32x4 acc = {0.f, 0.f, 0.f, 0.f};
#pragma unroll
    for (int kk = 0; kk < 16; ++kk) {
      if (kk + 3 < 16) ld8c(hrow, (kk + 3) * 32 + q * 8, aH[(kk + 3) & 3]);
      acc = groupMMv(aH[kk & 3], B3 + (kk >> 3) * 12672,
                     ln15 * 264 + (kk & 7) * 32 + q * 8, acc);
    }
    const int d = (w - 128) * 16 + ln15;
    float bb = wget(bctx, d, f32m);
#pragma unroll
    for (int r = 0; r < 4; ++r) {
      int br = v * 16 + q * 4 + r;
      ctx_store(ws, tier, (br * 512 + 511) * 512 + d, acc[r] + bb);
    }
  } else if (g == 0) {  // c_n hand-off (plain; kernel boundary flushes)
#pragma unroll
    for (int r = 0; r < 4; ++r) cwp[(v * 16 + q * 4 + r) * 512 + unit] = creg[r];
  }
}

// =================== persistent decoder ===================
// 256 WGs x 256, weight-stationary disjoint roles:
//   P1 wg 0..127 (Wx+Wh), P2 wg 128..159 (Win), P5 wg 160..191 (Wout),
//   P3 all, P4 wg 0..63. 5 arrive/wait barriers per step; P1's dinT-part in
//   the g5 window, P3's initial mask/ctx prefetch in the g2 window.
__global__ __launch_bounds__(256, 1) void dec_pers(
    const int* __restrict__ sent, const void* __restrict__ embD,
    const void* __restrict__ Wx, const void* __restrict__ bx,
    const void* __restrict__ Wh, const void* __restrict__ bh,
    const void* __restrict__ Wout, const void* __restrict__ bout,
    const void* __restrict__ Win, const void* __restrict__ bin,
    const void* __restrict__ V, char* __restrict__ ws,
    float* __restrict__ out, int tier) {
  __shared__ __align__(16) u16 B3[50688];        // 4 chunks x 12672
  __shared__ float accL[512];
  __shared__ float mlL[8];
  __shared__ float redA[256];
  __shared__ int redI[256];

  const int tid = threadIdx.x, wg = blockIdx.x;
  const int f32m = *(const int*)(ws + FLG_OFF);
  const int lane = tid & 63, v = tid >> 6, ln15 = lane & 15, q = lane >> 4;
  const int bA = v * 16 + ln15;
  const int sn = tid >> 4, sk = (tid & 15) * 16;
  float* hdT = (float*)(ws + HD_OFF);            // [64][512]
  float* aoT = (float*)(ws + AO_OFF);            // [64][1024]
  float* inp = (float*)(ws + INP_OFF);
  float* att = (float*)(ws + ATT_OFF);
  float* mask = (float*)(ws + MSK_OFF);
  float* pac = (float*)(ws + PAC_OFF);
  float* pml = (float*)(ws + PML_OFF);
  float* dinT = (float*)(ws + DIN_OFF);          // [64][256]
  const float* hnT = (const float*)(ws + HE_OFF);   // enc h_n, slot 0, [64][512]
  int bgen = 0;

  // P1 persistent c-state in registers
  const int g = ln15 & 3;
  const int unit = (wg < 128) ? (wg * 4 + (ln15 >> 2)) : 0;
  float creg[4];
  float bias = 0.0f;
  if (wg < 128) {
    const float* cwp = (const float*)(ws + CW_OFF);
#pragma unroll
    for (int r = 0; r < 4; ++r) creg[r] = cwp[(v * 16 + q * 4 + r) * 512 + unit];
    bias = wget(bx, (long)(g * 512 + unit), f32m) + wget(bh, (long)(g * 512 + unit), f32m);
  }
  // V is loop-invariant: hoist
  float vj[8];
#pragma unroll
  for (int j = 0; j < 8; ++j) vj[j] = wget(V, lane * 8 + j, f32m);

  // ---- stage weight chunks ONCE per role ----
  if (wg < 128) {
    const long grS = (long)((sn & 3) * 512 + wg * 4 + (sn >> 2));
    stage16(B3, Wx, f32m, grS * 256 + sk, sn, sk);
    stage16(B3 + 12672, Wh, f32m, grS * 512 + sk, sn, sk);
    stage16(B3 + 25344, Wh, f32m, grS * 512 + 256 + sk, sn, sk);
  } else if (wg < 160) {
    const long grS = (long)((wg - 128) * 16 + sn);
    stage16(B3, Win, f32m, grS * 512 + sk, sn, sk);
    stage16(B3 + 12672, Win, f32m, grS * 512 + 256 + sk, sn, sk);
  } else if (wg < 192) {
    const long grS = (long)((wg - 160) * 16 + sn);
#pragma unroll
    for (int cc = 0; cc < 4; ++cc)
      stage16(B3 + cc * 12672, Wout, f32m, grS * 1024 + cc * 256 + sk, sn, sk);
  }
  __syncthreads();

  // P1: dinT part for t=0 (acc carried in registers across phases)
  f32x4 acc1 = {0.f, 0.f, 0.f, 0.f};
  if (wg < 128) {
    const float* drow = dinT + bA * 256;
    float aD[4][8];
#pragma unroll
    for (int pf = 0; pf < 3; ++pf) ld8c(drow, pf * 32 + q * 8, aD[pf]);
#pragma unroll
    for (int ks = 0; ks < 8; ++ks) {
      if (ks + 3 < 8) ld8c(drow, (ks + 3) * 32 + q * 8, aD[(ks + 3) & 3]);
      acc1 = groupMMv(aD[ks & 3], B3, ln15 * 264 + ks * 32 + q * 8, acc1);
    }
  }

#pragma unroll 1
  for (int t = 0; t < 32; ++t) {
    // ---- P1: LSTM cell (h-half; dinT-half already in acc1) ----
    if (wg < 128) {
      const float* hrow = ((t == 0) ? hnT : (const float*)hdT) + bA * 512;
      float aH[4][8];
#pragma unroll
      for (int pf = 0; pf < 3; ++pf) ld8c(hrow, pf * 32 + q * 8, aH[pf]);
#pragma unroll
      for (int kk = 0; kk < 16; ++kk) {
        if (kk + 3 < 16) ld8c(hrow, (kk + 3) * 32 + q * 8, aH[(kk + 3) & 3]);
        acc1 = groupMMv(aH[kk & 3], B3 + (1 + (kk >> 3)) * 12672,
                        ln15 * 264 + (kk & 7) * 32 + q * 8, acc1);
      }
#pragma unroll
      for (int r = 0; r < 4; ++r) {
        int br = v * 16 + q * 4 + r;
        float val = acc1[r] + bias;
        float x1 = __shfl_xor(val, 1);
        float x2 = __shfl_xor(val, 2);
        float x3 = __shfl_xor(val, 3);
        float gi = sel4(val, x1, x2, x3, g);
        float gf = sel4(val, x1, x2, x3, g ^ 1);
        float gg = sel4(val, x1, x2, x3, g ^ 2);
        float go = sel4(val, x1, x2, x3, g ^ 3);
        float cn = sigf(gf) * creg[r] + sigf(gi) * tanhf(gg);
        float hv = sigf(go) * tanhf(cn);
        creg[r] = cn;
        if (g == 0) ast(aoT + br * 1024 + 512 + unit, hv);
      }
    }
    ++bgen;
    sbar_arrive(ws, FLD_OFF, wg, bgen);
    sbar_wait(ws, FLD_OFF, LDD_OFF, GEND_OFF, wg, 256, bgen);
    // ---- P2: inp = h_t @ Win^T + bin ----
    if (wg >= 128 && wg < 160) {
      const float* arow = aoT + bA * 1024;
      float aH[4][8];
#pragma unroll
      for (int pf = 0; pf < 3; ++pf) ld8c(arow, 512 + pf * 32 + q * 8, aH[pf]);
      f32x4 acc = {0.f, 0.f, 0.f, 0.f};
#pragma unroll
      for (int kk = 0; kk < 16; ++kk) {
        if (kk + 3 < 16) ld8c(arow, 512 + (kk + 3) * 32 + q * 8, aH[(kk + 3) & 3]);
        acc = groupMMv(aH[kk & 3], B3 + (kk >> 3) * 12672,
                       ln15 * 264 + (kk & 7) * 32 + q * 8, acc);
      }
      const int d = (wg - 128) * 16 + ln15;
      float bb = wget(bin, d, f32m);
#pragma unroll
      for (int r = 0; r < 4; ++r)
        ast(inp + (v * 16 + q * 4 + r) * 512 + d, acc[r] + bb);
    }
    ++bgen;
    sbar_arrive(ws, FLD_OFF, wg, bgen);
    // ---- g2 window: P3 initial mask/ctx prefetch (indep. of P2) ----
    const int b = wg & 63, qq = wg >> 6;
    const int s0 = qq * 128 + v * 32;
    float mkB[4];
    float cxB[4][8];
#pragma unroll
    for (int pf = 0; pf < 3; ++pf) {
      mkB[pf] = ald(mask + b * 512 + s0 + pf);
      ctx_load8(ws, tier, (b * 512 + s0 + pf) * 512 + lane * 8, cxB[pf]);
    }
    sbar_wait(ws, FLD_OFF, LDD_OFF, GEND_OFF, wg, 256, bgen);
    // ---- P3: attention (all 256 WGs), depth-3 rolling ctx prefetch ----
    {
      float ij[8];
      ld8c(inp + b * 512, lane * 8, ij);
      for (int i = tid; i < 512; i += 256) accL[i] = 0.0f;
      __syncthreads();
      float m = -1e30f, l = 0.0f;
      float oacc[8];
#pragma unroll
      for (int j = 0; j < 8; ++j) oacc[j] = 0.0f;
#pragma unroll 1
      for (int i0 = 0; i0 < 32; ++i0) {
        const int s = s0 + i0;
        if (i0 + 3 < 32) {
          mkB[(i0 + 3) & 3] = ald(mask + b * 512 + s + 3);
          ctx_load8(ws, tier, (b * 512 + s + 3) * 512 + lane * 8, cxB[(i0 + 3) & 3]);
        }
        float mkC = mkB[i0 & 3];
        const float (&cxC)[8] = cxB[i0 & 3];
        if (mkC == 0.0f) {
          if (lane == 0) ast(att + b * 512 + s, -1e30f);
        } else {
          float p = 0.0f;
#pragma unroll
          for (int j = 0; j < 8; ++j) p += vj[j] * tanhf(ij[j] + cxC[j]);
#pragma unroll
          for (int off = 1; off < 64; off <<= 1) p += __shfl_xor(p, off);
          if (lane == 0) ast(att + b * 512 + s, p);
          if (p <= m) {
            float e = expf(p - m);
            l += e;
#pragma unroll
            for (int j = 0; j < 8; ++j) oacc[j] += e * cxC[j];
          } else {
            float sc = expf(m - p);
            l = l * sc + 1.0f;
#pragma unroll
            for (int j = 0; j < 8; ++j) oacc[j] = oacc[j] * sc + cxC[j];
            m = p;
          }
        }
      }
      if (lane == 0) { mlL[v * 2] = m; mlL[v * 2 + 1] = l; }
      __syncthreads();
      float M = fmaxf(fmaxf(mlL[0], mlL[2]), fmaxf(mlL[4], mlL[6]));
      float Lq = 0.0f;
#pragma unroll
      for (int vv = 0; vv < 4; ++vv) Lq += mlL[vv * 2 + 1] * expf(mlL[vv * 2] - M);
      float scv = expf(m - M);
      for (int vv = 0; vv < 4; ++vv) {
        if (v == vv) {
#pragma unroll
          for (int j = 0; j < 8; ++j) accL[lane * 8 + j] += oacc[j] * scv;
        }
        __syncthreads();
      }
      for (int i = tid; i < 512; i += 256) ast(pac + (b * 4 + qq) * 512 + i, accL[i]);
      if (tid == 0) {
        ast(pml + (b * 4 + qq) * 2, M);
        ast(pml + (b * 4 + qq) * 2 + 1, Lq);
      }
    }
    ++bgen;
    sbar_arrive(ws, FLD_OFF, wg, bgen);
    sbar_wait(ws, FLD_OFF, LDD_OFF, GEND_OFF, wg, 256, bgen);
    // ---- P4: combine, alphas, argmax, next_in ----
    if (wg < 64) {
      const int bb = wg;
      float m0 = ald(pml + (bb * 4 + 0) * 2), m1 = ald(pml + (bb * 4 + 1) * 2);
      float m2 = ald(pml + (bb * 4 + 2) * 2), m3 = ald(pml + (bb * 4 + 3) * 2);
      float l0 = ald(pml + (bb * 4 + 0) * 2 + 1), l1 = ald(pml + (bb * 4 + 1) * 2 + 1);
      float l2 = ald(pml + (bb * 4 + 2) * 2 + 1), l3 = ald(pml + (bb * 4 + 3) * 2 + 1);
      float M = fmaxf(fmaxf(m0, m1), fmaxf(m2, m3));
      float e0 = expf(m0 - M), e1 = expf(m1 - M), e2 = expf(m2 - M), e3 = expf(m3 - M);
      float L = l0 * e0 + l1 * e1 + l2 * e2 + l3 * e3;
      L = fmaxf(L, 1e-30f);
      for (int h = tid; h < 512; h += 256) {
        float hv = (ald(pac + (bb * 4 + 0) * 512 + h) * e0 +
                    ald(pac + (bb * 4 + 1) * 512 + h) * e1 +
                    ald(pac + (bb * 4 + 2) * 512 + h) * e2 +
                    ald(pac + (bb * 4 + 3) * 512 + h) * e3) / L;
        ast(aoT + bb * 1024 + h, hv);
      }
      float bestA = -1.0f;
      int bestS = 0;
#pragma unroll
      for (int k = 0; k < 2; ++k) {
        int s = tid * 2 + k;
        float a = expf(ald(att + bb * 512 + s) - M) / L;
        out[(bb * 32 + t) * 512 + s] = a;
        if (a > bestA) { bestA = a; bestS = s; }
      }
      redA[tid] = bestA;
      redI[tid] = bestS;
      __syncthreads();
      for (int st = 128; st > 0; st >>= 1) {
        if (tid < st) {
          if (redA[tid + st] > redA[tid]) { redA[tid] = redA[tid + st]; redI[tid] = redI[tid + st]; }
        }
        __syncthreads();
      }
      int idx = redI[0];
      if (tid == 0) {
        ast(mask + bb * 512 + idx, 0.0f);
        out[1048576 + bb * 32 + t] = (float)idx;
      }
      int token = sent[idx * 64 + bb];
      ast(dinT + bb * 256 + tid, wget(embD, (long)token * 256 + tid, f32m));
    }
    ++bgen;
    sbar_arrive(ws, FLD_OFF, wg, bgen);
    sbar_wait(ws, FLD_OFF, LDD_OFF, GEND_OFF, wg, 256, bgen);
    // ---- P5: h_new = tanh([hidden|h_t] @ Wout^T + bout) ----
    if (wg >= 160 && wg < 192) {
      const float* arow = aoT + bA * 1024;
      float aH[4][8];
#pragma unroll
      for (int pf = 0; pf < 3; ++pf) ld8c(arow, pf * 32 + q * 8, aH[pf]);
      f32x4 acc = {0.f, 0.f, 0.f, 0.f};
#pragma unroll
      for (int kk = 0; kk < 32; ++kk) {
        if (kk + 3 < 32) ld8c(arow, (kk + 3) * 32 + q * 8, aH[(kk + 3) & 3]);
        acc = groupMMv(aH[kk & 3], B3 + (kk >> 3) * 12672,
                       ln15 * 264 + (kk & 7) * 32 + q * 8, acc);
      }
      const int d = (wg - 160) * 16 + ln15;
      float bb = wget(bout, d, f32m);
#pragma unroll
      for (int r = 0; r < 4; ++r)
        ast(hdT + (v * 16 + q * 4 + r) * 512 + d, tanhf(acc[r] + bb));
    }
    ++bgen;
    sbar_arrive(ws, FLD_OFF, wg, bgen);
    // ---- g5 window: P1's dinT part for t+1 (dinT visible since g4) ----
    if (wg < 128 && t < 31) {
      const float* drow = dinT + bA * 256;
      float aD[4][8];
#pragma unroll
      for (int pf = 0; pf < 3; ++pf) ld8c(drow, pf * 32 + q * 8, aD[pf]);
      f32x4 accn = {0.f, 0.f, 0.f, 0.f};
#pragma unroll
      for (int ks = 0; ks < 8; ++ks) {
        if (ks + 3 < 8) ld8c(drow, (ks + 3) * 32 + q * 8, aD[(ks + 3) & 3]);
        accn = groupMMv(aD[ks & 3], B3, ln15 * 264 + ks * 32 + q * 8, accn);
      }
      acc1 = accn;
    }
    if (t < 31) sbar_wait(ws, FLD_OFF, LDD_OFF, GEND_OFF, wg, 256, bgen);
  }
}

// =================== diagnostic ===================
__global__ void diag_kernel(char* ws, float* out, int wsMiB) {
  if (threadIdx.x == 0 && blockIdx.x == 0) {
    int f = *(int*)(ws + FLG_OFF);
    out[0] = (float)(wsMiB + 2000 * f);
  }
}

extern "C" void kernel_launch(void* const* d_in, const int* in_sizes, int n_in,
                              void* d_out, int out_size, void* d_ws, size_t ws_size,
                              hipStream_t stream) {
  (void)in_sizes; (void)n_in; (void)out_size;
  const int* sent = (const int*)d_in[0];
  const void* embE = d_in[1];
  const void* embD = d_in[2];
  const void* Wih = d_in[3];
  const void* Whh = d_in[4];
  const void* bih = d_in[5];
  const void* bhh = d_in[6];
  const void* din0 = d_in[7];
  const void* Wx = d_in[8];
  const void* bx = d_in[9];
  const void* Wh = d_in[10];
  const void* bh = d_in[11];
  const void* Wout = d_in[12];
  const void* bout = d_in[13];
  const void* Win = d_in[14];
  const void* bin = d_in[15];
  const void* Wctx = d_in[16];
  const void* bctx = d_in[17];
  const void* V = d_in[18];
  char* ws = (char*)d_ws;
  float* out = (float*)d_out;

  int tier;
  if (ws_size >= (size_t)NEED_T0) tier = 0;
  else if (ws_size >= (size_t)NEED_T1) tier = 1;
  else if (ws_size >= (size_t)NEED_T2) tier = 2;
  else tier = 3;

  prep_detect<<<dim3(1), dim3(256), 0, stream>>>(embE, ws);
  prep_init<<<dim3(64), dim3(256), 0, stream>>>(din0, ws);
  enc_pers<<<dim3(160), dim3(256), 0, stream>>>(sent, embE, Wih, Whh, bih, bhh,
                                                Wctx, bctx, ws, tier);
  dec_pers<<<dim3(256), dim3(256), 0, stream>>>(sent, embD, Wx, bx, Wh, bh, Wout, bout,
                                                Win, bin, V, ws, out, tier);
  if (tier >= 2)
    diag_kernel<<<dim3(1), dim3(64), 0, stream>>>(ws, out, (int)(ws_size >> 20));
}

// Round 3
// 8893.118 us; speedup vs baseline: 1.2603x; 1.2603x over previous
//
#include <hip/hip_runtime.h>
#include <hip/hip_bf16.h>

// PointerNet MI355X — Round 13: R11 coalesced [K][64] layouts + R12's latency
// structure. (R12's batch-major [64][K] switch destroyed coalescing: lanes
// 512 floats apart -> 64 lines per load; reverted.) Kept from R12: depth-3
// rolling prefetch (coalesced ld8T), arrive/wait-split barrier with window
// work (enc emb-half, dec dinT-part + ctx prefetch), split8v. New: flat
// 1-hop barrier (one wave polls all flags; no leader tree).
// Arithmetic op-identical to R10/R11/R12 (absmax expected 1.525879e-05).

typedef unsigned short u16;
typedef unsigned long long u64;
typedef __bf16 bf16_t;
typedef bf16_t bf16x8 __attribute__((ext_vector_type(8)));
typedef float f32x4 __attribute__((ext_vector_type(4)));

#define MFMA16(a, b, c) __builtin_amdgcn_mfma_f32_16x16x32_bf16(a, b, c, 0, 0, 0)
#define AGENT __HIP_MEMORY_SCOPE_AGENT

// ---------------- ws layout (bytes) ----------------
#define FLG_OFF   64u
#define GENE_OFF  128u
#define LDE_OFF   192u           // (unused in flat barrier; kept zeroed)
#define FLE_OFF   1216u          // 160 x 64B flag lines (encoder)
#define GEND_OFF  11456u
#define LDD_OFF   11520u
#define FLD_OFF   12544u         // 256 x 64B flag lines (decoder)
#define BAR_END   28928u
#define HE_OFF    32768u         // f32 [2][512][64] enc h ping-pong TRANSPOSED
#define CW_OFF    294912u        // f32 [64][512] c hand-off enc->dec
#define HD_OFF    425984u        // f32 [512][64] dec h carry TRANSPOSED
#define AO_OFF    557056u        // f32 [1024][64] concat [hidden|h_t] TRANSPOSED
#define INP_OFF   819200u        // f32 [64][512]
#define ATT_OFF   950272u        // f32 [64][512]
#define MSK_OFF   1081344u       // f32 [64][512]
#define PAC_OFF   1212416u       // f32 [64][4][512]
#define PML_OFF   1736704u       // f32 [64][4][2]
#define DIN_OFF   1740800u       // f32 [256][64] TRANSPOSED
#define CTX_OFF   2097152u       // tier0 f32 64MiB; tier1 bf16+i8
#define CTXL_OFF  (CTX_OFF + 33554432u)
#define NEED_T0   (CTX_OFF + 67108864u)
#define NEED_T1   (CTX_OFF + 50331648u)
#define NEED_T2   (CTX_OFF + 33554432u)

__device__ __forceinline__ float bf2f(u16 b) {
  union { unsigned u; float f; } c; c.u = ((unsigned)b) << 16; return c.f;
}
__device__ __forceinline__ u16 f2bf(float x) {
  union { float f; unsigned u; } c; c.f = x;
  unsigned r = c.u + 0x7FFFu + ((c.u >> 16) & 1u);
  return (u16)(r >> 16);
}
__device__ __forceinline__ float sigf(float x) { return 1.0f / (1.0f + expf(-x)); }
__device__ __forceinline__ float sel4(float a0, float a1, float a2, float a3, int j) {
  float r = (j == 1) ? a1 : a0;
  r = (j == 2) ? a2 : r;
  r = (j == 3) ? a3 : r;
  return r;
}
__device__ __forceinline__ float wget(const void* p, long i, int f32m) {
  return f32m ? ((const float*)p)[i] : bf2f(((const u16*)p)[i]);
}
__device__ __forceinline__ void ld8(const void* p, long i, int f32m, float (&o)[8]) {
  if (f32m) {
    const float4* q = (const float4*)((const float*)p + i);
    float4 a = q[0], b = q[1];
    o[0] = a.x; o[1] = a.y; o[2] = a.z; o[3] = a.w;
    o[4] = b.x; o[5] = b.y; o[6] = b.z; o[7] = b.w;
  } else {
    uint4 u = *(const uint4*)((const u16*)p + i);
    unsigned ww[4] = {u.x, u.y, u.z, u.w};
#pragma unroll
    for (int k = 0; k < 4; ++k) {
      o[2 * k] = bf2f((u16)(ww[k] & 0xFFFFu));
      o[2 * k + 1] = bf2f((u16)(ww[k] >> 16));
    }
  }
}
// relaxed agent-scope atomics (sc0/sc1: write-through + cache-bypass)
__device__ __forceinline__ float ald(const float* p) {
  return __hip_atomic_load(p, __ATOMIC_RELAXED, AGENT);
}
__device__ __forceinline__ void ast(float* p, float v) {
  __hip_atomic_store(p, v, __ATOMIC_RELAXED, AGENT);
}
__device__ __forceinline__ int aldi(const int* p) {
  return __hip_atomic_load(p, __ATOMIC_RELAXED, AGENT);
}
// transposed coalesced read: a8[j] = T[kb+j][bA]  (lane stride 1 -> 1-2 lines)
__device__ __forceinline__ void ld8T(const float* T, int kb, int bA, float (&o)[8]) {
  const float* p = T + kb * 64 + bA;
#pragma unroll
  for (int j = 0; j < 8; ++j) o[j] = ald(p + j * 64);
}

// 3-plane truncation split (scalar form; staging + hand-offs)
__device__ __forceinline__ void split3(float x, u16& h, u16& l, u16& l2) {
  union { float f; unsigned u; } c; c.f = x;
  h = (u16)(c.u >> 16);
  float r = x - bf2f(h);
  union { float f; unsigned u; } e; e.f = r;
  l = (u16)(e.u >> 16);
  float r2 = r - bf2f(l);
  union { float f; unsigned u; } g; g.f = r2;
  l2 = (u16)(g.u >> 16);
}
// vector form: identical plane values, packs pairs with bit-ops
__device__ __forceinline__ void split8v(const float (&a)[8], bf16x8& H, bf16x8& L,
                                        bf16x8& L2) {
  union { unsigned u[4]; bf16x8 v; } hh, ll, mm;
#pragma unroll
  for (int k = 0; k < 4; ++k) {
    union { float f; unsigned u; } x0, x1;
    x0.f = a[2 * k]; x1.f = a[2 * k + 1];
    unsigned t0 = x0.u & 0xFFFF0000u, t1 = x1.u & 0xFFFF0000u;
    union { unsigned u; float f; } b0, b1; b0.u = t0; b1.u = t1;
    float r0 = x0.f - b0.f, r1 = x1.f - b1.f;
    union { float f; unsigned u; } e0, e1; e0.f = r0; e1.f = r1;
    unsigned s0 = e0.u & 0xFFFF0000u, s1 = e1.u & 0xFFFF0000u;
    union { unsigned u; float f; } c0, c1; c0.u = s0; c1.u = s1;
    float q0 = r0 - c0.f, q1 = r1 - c1.f;
    union { float f; unsigned u; } g0, g1; g0.f = q0; g1.f = q1;
    hh.u[k] = t1 | (x0.u >> 16);
    ll.u[k] = s1 | (e0.u >> 16);
    mm.u[k] = (g1.u & 0xFFFF0000u) | (g0.u >> 16);
  }
  H = hh.v; L = ll.v; L2 = mm.v;
}
__device__ __forceinline__ f32x4 mfma6(const bf16x8& ah, const bf16x8& al,
                                       const bf16x8& al2, const bf16x8& bh,
                                       const bf16x8& bl, const bf16x8& bl2, f32x4 acc) {
  acc = MFMA16(ah, bh, acc);
  acc = MFMA16(al, bh, acc);
  acc = MFMA16(ah, bl, acc);
  acc = MFMA16(al, bl, acc);
  acc = MFMA16(ah, bl2, acc);
  acc = MFMA16(al2, bh, acc);
  return acc;
}
__device__ __forceinline__ f32x4 groupMMv(const float (&a8)[8], const u16* B3c, int bo,
                                          f32x4 acc) {
  bf16x8 H, L, L2;
  split8v(a8, H, L, L2);
  return mfma6(H, L, L2, *(const bf16x8*)(B3c + bo), *(const bf16x8*)(B3c + 4224 + bo),
               *(const bf16x8*)(B3c + 8448 + bo), acc);
}
__device__ __forceinline__ void stage16(u16* B3, const void* W, int f32m,
                                        long src, int n, int k16) {
  float t0[8], t1[8];
  ld8(W, src, f32m, t0);
  ld8(W, src + 8, f32m, t1);
#pragma unroll
  for (int j = 0; j < 8; ++j) {
    u16 h, l, l2; split3(t0[j], h, l, l2);
    int o = n * 264 + k16 + j;
    B3[o] = h; B3[4224 + o] = l; B3[8448 + o] = l2;
  }
#pragma unroll
  for (int j = 0; j < 8; ++j) {
    u16 h, l, l2; split3(t1[j], h, l, l2);
    int o = n * 264 + k16 + 8 + j;
    B3[o] = h; B3[4224 + o] = l; B3[8448 + o] = l2;
  }
}

// ---- ctx codec (cross-kernel hand-off: plain stores/loads) ----
__device__ __forceinline__ void ctx_store(char* ws, int tier, int oi, float x) {
  if (tier == 0) { ((float*)(ws + CTX_OFF))[oi] = x; return; }
  if (tier >= 3) return;
  u16 hi = f2bf(x);
  ((u16*)(ws + CTX_OFF))[oi] = hi;
  if (tier == 1) {
    unsigned e = hi & 0x7F80u; if (e == 0) e = 0x0080u;
    float us = bf2f((u16)e) * 0.00390625f;
    float r = (x - bf2f(hi)) / us;
    int q = (int)__float2int_rn(r * 254.0f);
    q = max(-127, min(127, q));
    ((signed char*)(ws + CTXL_OFF))[oi] = (signed char)q;
  }
}
__device__ __forceinline__ void ctx_load8(const char* ws, int tier, int oi, float (&cx)[8]) {
  if (tier == 0) {
    const float4* p = (const float4*)((const float*)(ws + CTX_OFF) + oi);
    float4 a = p[0], b = p[1];
    cx[0] = a.x; cx[1] = a.y; cx[2] = a.z; cx[3] = a.w;
    cx[4] = b.x; cx[5] = b.y; cx[6] = b.z; cx[7] = b.w;
    return;
  }
  if (tier >= 3) {
#pragma unroll
    for (int j = 0; j < 8; ++j) cx[j] = 0.0f;
    return;
  }
  uint4 hu = *(const uint4*)((const u16*)(ws + CTX_OFF) + oi);
  unsigned hw[4] = {hu.x, hu.y, hu.z, hu.w};
  u16 h[8];
#pragma unroll
  for (int k = 0; k < 4; ++k) { h[2*k] = (u16)(hw[k] & 0xFFFFu); h[2*k+1] = (u16)(hw[k] >> 16); }
#pragma unroll
  for (int j = 0; j < 8; ++j) cx[j] = bf2f(h[j]);
  if (tier == 1) {
    const signed char* lp = (const signed char*)(ws + CTXL_OFF) + oi;
#pragma unroll
    for (int j = 0; j < 8; ++j) {
      unsigned e = h[j] & 0x7F80u; if (e == 0) e = 0x0080u;
      float us = bf2f((u16)e) * 0.00390625f;
      cx[j] += (float)lp[j] * us * (1.0f / 254.0f);
    }
  }
}

// ---- flat fence-free grid barrier, split arrive/wait (1 L3 hop) ----
__device__ __forceinline__ void fbar_arrive(char* ws, unsigned flOff, int wg, int gen) {
  __builtin_amdgcn_s_waitcnt(0);   // payload sc1 stores drained to L3
  __syncthreads();
  if (threadIdx.x == 0)
    __hip_atomic_store((int*)(ws + flOff) + wg * 16, gen, __ATOMIC_RELAXED, AGENT);
}
__device__ __forceinline__ void fbar_wait(char* ws, unsigned flOff, int nwg, int gen) {
  const int tid = threadIdx.x;
  if (tid < 64) {                  // one wave polls all flags directly
    const int* fl = (const int*)(ws + flOff);
    for (int i = tid; i < nwg; i += 64) {
      const int* f = fl + i * 16;
      while (aldi(f) < gen) __builtin_amdgcn_s_sleep(1);
    }
  }
  __syncthreads();
}

// =================== prep ===================
__global__ void prep_detect(const void* embE, char* ws) {
  __shared__ int cnt;
  if (threadIdx.x == 0) cnt = 0;
  __syncthreads();
  const u16* p = (const u16*)embE;
  int c = 0;
  for (int i = threadIdx.x; i < 4096; i += 256) {
    float v = bf2f(p[i]);
    if (!(fabsf(v) < 4.0f)) c++;
  }
  atomicAdd(&cnt, c);
  __syncthreads();
  if (threadIdx.x == 0) *(int*)(ws + FLG_OFF) = (cnt > 200) ? 1 : 0;
}

__global__ void prep_init(const void* din0, char* ws) {
  const int f32m = *(const int*)(ws + FLG_OFF);
  int i0 = blockIdx.x * 256 + threadIdx.x;
  int stride = gridDim.x * 256;
  int* bars = (int*)ws;
  for (int i = i0; i < (int)((BAR_END - GENE_OFF) / 4); i += stride)
    bars[(GENE_OFF / 4) + i] = 0;
  float* h0 = (float*)(ws + HE_OFF);             // slot 0 only
  float* mask = (float*)(ws + MSK_OFF);
  float* dinT = (float*)(ws + DIN_OFF);          // [256][64]
  for (int i = i0; i < 32768; i += stride) { h0[i] = 0.0f; mask[i] = 1.0f; }
  for (int i = i0; i < 16384; i += stride) dinT[i] = wget(din0, i >> 6, f32m);
}

// =================== persistent encoder ===================
// grid 160 x 256. WGs 0..127: gates (weights LDS-stationary, c in regs).
// WGs 128..159: ctx row t-1. h ping-pong [2][512][64] TRANSPOSED (coalesced).
// Per step: emb half of GEMM in the arrive->wait window; h half via depth-3
// rolling coalesced prefetch.
__global__ __launch_bounds__(256, 1) void enc_pers(
    const int* __restrict__ sent, const void* __restrict__ embE,
    const void* __restrict__ Wih, const void* __restrict__ Whh,
    const void* __restrict__ bih, const void* __restrict__ bhh,
    const void* __restrict__ Wctx, const void* __restrict__ bctx,
    char* __restrict__ ws, int tier) {
  __shared__ __align__(16) u16 B3[38016];        // 3 chunks x 12672
  const int tid = threadIdx.x, w = blockIdx.x;
  const int f32m = *(const int*)(ws + FLG_OFF);
  const int lane = tid & 63, v = tid >> 6, ln15 = lane & 15, q = lane >> 4;
  const int bA = v * 16 + ln15;
  const int sn = tid >> 4, sk = (tid & 15) * 16;
  float* heT = (float*)(ws + HE_OFF);
  float* cwp = (float*)(ws + CW_OFF);

  const int g = ln15 & 3;
  const int unit = w * 4 + (ln15 >> 2);        // gate WGs only
  float creg[4];
#pragma unroll
  for (int r = 0; r < 4; ++r) creg[r] = 0.0f;
  float bias = 0.0f;

  // ---- stage all weight chunks ONCE (loop-invariant) ----
  if (w < 128) {
    long grC = (long)(g * 512 + unit);
    bias = wget(bih, grC, f32m) + wget(bhh, grC, f32m);
    const long grS = (long)((sn & 3) * 512 + w * 4 + (sn >> 2));
    stage16(B3, Wih, f32m, grS * 256 + sk, sn, sk);
    stage16(B3 + 12672, Whh, f32m, grS * 512 + sk, sn, sk);
    stage16(B3 + 25344, Whh, f32m, grS * 512 + 256 + sk, sn, sk);
  } else {
    const long grS = (long)((w - 128) * 16 + sn);
    stage16(B3, Wctx, f32m, grS * 512 + sk, sn, sk);
    stage16(B3 + 12672, Wctx, f32m, grS * 512 + 256 + sk, sn, sk);
  }
  __syncthreads();

#pragma unroll 1
  for (int t = 0; t < 512; ++t) {
    const int slot = t & 1;
    const float* hsT = heT + slot * 32768;     // [512][64]
    if (w < 128) {
      // ---- emb half: independent of h_{t-1}; overlaps barrier skew ----
      const int tok = sent[t * 64 + bA];
      f32x4 acc = {0.f, 0.f, 0.f, 0.f};
      {
        float aE[4][8];
#pragma unroll
        for (int pf = 0; pf < 3; ++pf)
          ld8(embE, (long)tok * 256 + pf * 32 + q * 8, f32m, aE[pf]);
#pragma unroll
        for (int ks = 0; ks < 8; ++ks) {
          if (ks + 3 < 8) ld8(embE, (long)tok * 256 + (ks + 3) * 32 + q * 8, f32m,
                              aE[(ks + 3) & 3]);
          acc = groupMMv(aE[ks & 3], B3, ln15 * 264 + ks * 32 + q * 8, acc);
        }
      }
      if (t) fbar_wait(ws, FLE_OFF, 160, t);
      // ---- h half: depth-3 rolling coalesced prefetch ----
      {
        float aH[4][8];
#pragma unroll
        for (int pf = 0; pf < 3; ++pf) ld8T(hsT, pf * 32 + q * 8, bA, aH[pf]);
#pragma unroll
        for (int kk = 0; kk < 16; ++kk) {
          if (kk + 3 < 16) ld8T(hsT, (kk + 3) * 32 + q * 8, bA, aH[(kk + 3) & 3]);
          acc = groupMMv(aH[kk & 3], B3 + (1 + (kk >> 3)) * 12672,
                         ln15 * 264 + (kk & 7) * 32 + q * 8, acc);
        }
      }
      float* hdTs = heT + (slot ^ 1) * 32768;
#pragma unroll
      for (int r = 0; r < 4; ++r) {
        int br = v * 16 + q * 4 + r;
        float val = acc[r] + bias;
        float x1 = __shfl_xor(val, 1);
        float x2 = __shfl_xor(val, 2);
        float x3 = __shfl_xor(val, 3);
        float gi = sel4(val, x1, x2, x3, g);
        float gf = sel4(val, x1, x2, x3, g ^ 1);
        float gg = sel4(val, x1, x2, x3, g ^ 2);
        float go = sel4(val, x1, x2, x3, g ^ 3);
        float cn = sigf(gf) * creg[r] + sigf(gi) * tanhf(gg);
        float hv = sigf(go) * tanhf(cn);
        creg[r] = cn;                        // all quad lanes track identical c
        if (g == 0) ast(hdTs + unit * 64 + br, hv);
      }
    } else {
      if (t) {
        fbar_wait(ws, FLE_OFF, 160, t);
        float aH[4][8];
#pragma unroll
        for (int pf = 0; pf < 3; ++pf) ld8T(hsT, pf * 32 + q * 8, bA, aH[pf]);
        f32x4 acc = {0.f, 0.f, 0.f, 0.f};
#pragma unroll
        for (int kk = 0; kk < 16; ++kk) {
          if (kk + 3 < 16) ld8T(hsT, (kk + 3) * 32 + q * 8, bA, aH[(kk + 3) & 3]);
          acc = groupMMv(aH[kk & 3], B3 + (kk >> 3) * 12672,
                         ln15 * 264 + (kk & 7) * 32 + q * 8, acc);
        }
        const int d = (w - 128) * 16 + ln15;
        float bb = wget(bctx, d, f32m);
#pragma unroll
        for (int r = 0; r < 4; ++r) {
          int br = v * 16 + q * 4 + r;
          ctx_store(ws, tier, (br * 512 + (t - 1)) * 512 + d, acc[r] + bb);
        }
      }
    }
    fbar_arrive(ws, FLE_OFF, w, t + 1);
  }
  if (w >= 128) {
    // tail: ctx row 511 from h_511 (slot 0)
    fbar_wait(ws, FLE_OFF, 160, 512);
    const float* hsT = heT;                    // slot 0
    float aH[4][8];
#pragma unroll
    for (int pf = 0; pf < 3; ++pf) ld8T(hsT, pf * 32 + q * 8, bA, aH[pf]);
    f32x4 acc = {0.f, 0.f, 0.f, 0.f};
#pragma unroll
    for (int kk = 0; kk < 16; ++kk) {
      if (kk + 3 < 16) ld8T(hsT, (kk + 3) * 32 + q * 8, bA, aH[(kk + 3) & 3]);
      acc = groupMMv(aH[kk & 3], B3 + (kk >> 3) * 12672,
                     ln15 * 264 + (kk & 7) * 32 + q * 8, acc);
    }
    const int d = (w - 128) * 16 + ln15;
    float bb = wget(bctx, d, f32m);
#pragma unroll
    for (int r = 0; r < 4; ++r) {
      int br = v * 16 + q * 4 + r;
      ctx_store(ws, tier, (br * 512 + 511) * 512 + d, acc[r] + bb);
    }
  } else if (g == 0) {  // c_n hand-off (plain; kernel boundary flushes)
#pragma unroll
    for (int r = 0; r < 4; ++r) cwp[(v * 16 + q * 4 + r) * 512 + unit] = creg[r];
  }
}

// =================== persistent decoder ===================
// 256 WGs x 256, weight-stationary disjoint roles:
//   P1 wg 0..127 (Wx+Wh), P2 wg 128..159 (Win), P5 wg 160..191 (Wout),
//   P3 all, P4 wg 0..63. 5 flat arrive/wait barriers/step; P1 dinT-part in
//   g5 window, P3 initial mask/ctx prefetch in g2 window. [K][64] layouts.
__global__ __launch_bounds__(256, 1) void dec_pers(
    const int* __restrict__ sent, const void* __restrict__ embD,
    const void* __restrict__ Wx, const void* __restrict__ bx,
    const void* __restrict__ Wh, const void* __restrict__ bh,
    const void* __restrict__ Wout, const void* __restrict__ bout,
    const void* __restrict__ Win, const void* __restrict__ bin,
    const void* __restrict__ V, char* __restrict__ ws,
    float* __restrict__ out, int tier) {
  __shared__ __align__(16) u16 B3[50688];        // 4 chunks x 12672
  __shared__ float accL[512];
  __shared__ float mlL[8];
  __shared__ float redA[256];
  __shared__ int redI[256];

  const int tid = threadIdx.x, wg = blockIdx.x;
  const int f32m = *(const int*)(ws + FLG_OFF);
  const int lane = tid & 63, v = tid >> 6, ln15 = lane & 15, q = lane >> 4;
  const int bA = v * 16 + ln15;
  const int sn = tid >> 4, sk = (tid & 15) * 16;
  float* hdT = (float*)(ws + HD_OFF);            // [512][64]
  float* aoT = (float*)(ws + AO_OFF);            // [1024][64]
  float* inp = (float*)(ws + INP_OFF);
  float* att = (float*)(ws + ATT_OFF);
  float* mask = (float*)(ws + MSK_OFF);
  float* pac = (float*)(ws + PAC_OFF);
  float* pml = (float*)(ws + PML_OFF);
  float* dinT = (float*)(ws + DIN_OFF);          // [256][64]
  const float* hnT = (const float*)(ws + HE_OFF);   // enc h_n, slot 0, [512][64]
  int bgen = 0;

  // P1 persistent c-state in registers
  const int g = ln15 & 3;
  const int unit = (wg < 128) ? (wg * 4 + (ln15 >> 2)) : 0;
  float creg[4];
  float bias = 0.0f;
  if (wg < 128) {
    const float* cwp = (const float*)(ws + CW_OFF);
#pragma unroll
    for (int r = 0; r < 4; ++r) creg[r] = cwp[(v * 16 + q * 4 + r) * 512 + unit];
    bias = wget(bx, (long)(g * 512 + unit), f32m) + wget(bh, (long)(g * 512 + unit), f32m);
  }
  // V is loop-invariant: hoist
  float vj[8];
#pragma unroll
  for (int j = 0; j < 8; ++j) vj[j] = wget(V, lane * 8 + j, f32m);

  // ---- stage weight chunks ONCE per role ----
  if (wg < 128) {
    const long grS = (long)((sn & 3) * 512 + wg * 4 + (sn >> 2));
    stage16(B3, Wx, f32m, grS * 256 + sk, sn, sk);
    stage16(B3 + 12672, Wh, f32m, grS * 512 + sk, sn, sk);
    stage16(B3 + 25344, Wh, f32m, grS * 512 + 256 + sk, sn, sk);
  } else if (wg < 160) {
    const long grS = (long)((wg - 128) * 16 + sn);
    stage16(B3, Win, f32m, grS * 512 + sk, sn, sk);
    stage16(B3 + 12672, Win, f32m, grS * 512 + 256 + sk, sn, sk);
  } else if (wg < 192) {
    const long grS = (long)((wg - 160) * 16 + sn);
#pragma unroll
    for (int cc = 0; cc < 4; ++cc)
      stage16(B3 + cc * 12672, Wout, f32m, grS * 1024 + cc * 256 + sk, sn, sk);
  }
  __syncthreads();

  // P1: dinT part for t=0 (acc carried in registers across phases)
  f32x4 acc1 = {0.f, 0.f, 0.f, 0.f};
  if (wg < 128) {
    float aD[4][8];
#pragma unroll
    for (int pf = 0; pf < 3; ++pf) ld8T(dinT, pf * 32 + q * 8, bA, aD[pf]);
#pragma unroll
    for (int ks = 0; ks < 8; ++ks) {
      if (ks + 3 < 8) ld8T(dinT, (ks + 3) * 32 + q * 8, bA, aD[(ks + 3) & 3]);
      acc1 = groupMMv(aD[ks & 3], B3, ln15 * 264 + ks * 32 + q * 8, acc1);
    }
  }

#pragma unroll 1
  for (int t = 0; t < 32; ++t) {
    // ---- P1: LSTM cell (h-half; dinT-half already in acc1) ----
    if (wg < 128) {
      const float* hsT = (t == 0) ? hnT : (const float*)hdT;
      float aH[4][8];
#pragma unroll
      for (int pf = 0; pf < 3; ++pf) ld8T(hsT, pf * 32 + q * 8, bA, aH[pf]);
#pragma unroll
      for (int kk = 0; kk < 16; ++kk) {
        if (kk + 3 < 16) ld8T(hsT, (kk + 3) * 32 + q * 8, bA, aH[(kk + 3) & 3]);
        acc1 = groupMMv(aH[kk & 3], B3 + (1 + (kk >> 3)) * 12672,
                        ln15 * 264 + (kk & 7) * 32 + q * 8, acc1);
      }
#pragma unroll
      for (int r = 0; r < 4; ++r) {
        int br = v * 16 + q * 4 + r;
        float val = acc1[r] + bias;
        float x1 = __shfl_xor(val, 1);
        float x2 = __shfl_xor(val, 2);
        float x3 = __shfl_xor(val, 3);
        float gi = sel4(val, x1, x2, x3, g);
        float gf = sel4(val, x1, x2, x3, g ^ 1);
        float gg = sel4(val, x1, x2, x3, g ^ 2);
        float go = sel4(val, x1, x2, x3, g ^ 3);
        float cn = sigf(gf) * creg[r] + sigf(gi) * tanhf(gg);
        float hv = sigf(go) * tanhf(cn);
        creg[r] = cn;
        if (g == 0) ast(aoT + (512 + unit) * 64 + br, hv);
      }
    }
    ++bgen;
    fbar_arrive(ws, FLD_OFF, wg, bgen);
    fbar_wait(ws, FLD_OFF, 256, bgen);
    // ---- P2: inp = h_t @ Win^T + bin ----
    if (wg >= 128 && wg < 160) {
      float aH[4][8];
#pragma unroll
      for (int pf = 0; pf < 3; ++pf) ld8T(aoT, 512 + pf * 32 + q * 8, bA, aH[pf]);
      f32x4 acc = {0.f, 0.f, 0.f, 0.f};
#pragma unroll
      for (int kk = 0; kk < 16; ++kk) {
        if (kk + 3 < 16) ld8T(aoT, 512 + (kk + 3) * 32 + q * 8, bA, aH[(kk + 3) & 3]);
        acc = groupMMv(aH[kk & 3], B3 + (kk >> 3) * 12672,
                       ln15 * 264 + (kk & 7) * 32 + q * 8, acc);
      }
      const int d = (wg - 128) * 16 + ln15;
      float bb = wget(bin, d, f32m);
#pragma unroll
      for (int r = 0; r < 4; ++r)
        ast(inp + (v * 16 + q * 4 + r) * 512 + d, acc[r] + bb);
    }
    ++bgen;
    fbar_arrive(ws, FLD_OFF, wg, bgen);
    // ---- g2 window: P3 initial mask/ctx prefetch (indep. of P2) ----
    const int b = wg & 63, qq = wg >> 6;
    const int s0 = qq * 128 + v * 32;
    float mkB[4];
    float cxB[4][8];
#pragma unroll
    for (int pf = 0; pf < 3; ++pf) {
      mkB[pf] = ald(mask + b * 512 + s0 + pf);
      ctx_load8(ws, tier, (b * 512 + s0 + pf) * 512 + lane * 8, cxB[pf]);
    }
    fbar_wait(ws, FLD_OFF, 256, bgen);
    // ---- P3: attention (all 256 WGs), depth-3 rolling ctx prefetch ----
    {
      float ij[8];
#pragma unroll
      for (int j = 0; j < 8; ++j) ij[j] = ald(inp + b * 512 + lane * 8 + j);
      for (int i = tid; i < 512; i += 256) accL[i] = 0.0f;
      __syncthreads();
      float m = -1e30f, l = 0.0f;
      float oacc[8];
#pragma unroll
      for (int j = 0; j < 8; ++j) oacc[j] = 0.0f;
#pragma unroll 1
      for (int i0 = 0; i0 < 32; ++i0) {
        const int s = s0 + i0;
        if (i0 + 3 < 32) {
          mkB[(i0 + 3) & 3] = ald(mask + b * 512 + s + 3);
          ctx_load8(ws, tier, (b * 512 + s + 3) * 512 + lane * 8, cxB[(i0 + 3) & 3]);
        }
        float mkC = mkB[i0 & 3];
        const float (&cxC)[8] = cxB[i0 & 3];
        if (mkC == 0.0f) {
          if (lane == 0) ast(att + b * 512 + s, -1e30f);
        } else {
          float p = 0.0f;
#pragma unroll
          for (int j = 0; j < 8; ++j) p += vj[j] * tanhf(ij[j] + cxC[j]);
#pragma unroll
          for (int off = 1; off < 64; off <<= 1) p += __shfl_xor(p, off);
          if (lane == 0) ast(att + b * 512 + s, p);
          if (p <= m) {
            float e = expf(p - m);
            l += e;
#pragma unroll
            for (int j = 0; j < 8; ++j) oacc[j] += e * cxC[j];
          } else {
            float sc = expf(m - p);
            l = l * sc + 1.0f;
#pragma unroll
            for (int j = 0; j < 8; ++j) oacc[j] = oacc[j] * sc + cxC[j];
            m = p;
          }
        }
      }
      if (lane == 0) { mlL[v * 2] = m; mlL[v * 2 + 1] = l; }
      __syncthreads();
      float M = fmaxf(fmaxf(mlL[0], mlL[2]), fmaxf(mlL[4], mlL[6]));
      float Lq = 0.0f;
#pragma unroll
      for (int vv = 0; vv < 4; ++vv) Lq += mlL[vv * 2 + 1] * expf(mlL[vv * 2] - M);
      float scv = expf(m - M);
      for (int vv = 0; vv < 4; ++vv) {
        if (v == vv) {
#pragma unroll
          for (int j = 0; j < 8; ++j) accL[lane * 8 + j] += oacc[j] * scv;
        }
        __syncthreads();
      }
      for (int i = tid; i < 512; i += 256) ast(pac + (b * 4 + qq) * 512 + i, accL[i]);
      if (tid == 0) {
        ast(pml + (b * 4 + qq) * 2, M);
        ast(pml + (b * 4 + qq) * 2 + 1, Lq);
      }
    }
    ++bgen;
    fbar_arrive(ws, FLD_OFF, wg, bgen);
    fbar_wait(ws, FLD_OFF, 256, bgen);
    // ---- P4: combine, alphas, argmax, next_in ----
    if (wg < 64) {
      const int bb = wg;
      float m0 = ald(pml + (bb * 4 + 0) * 2), m1 = ald(pml + (bb * 4 + 1) * 2);
      float m2 = ald(pml + (bb * 4 + 2) * 2), m3 = ald(pml + (bb * 4 + 3) * 2);
      float l0 = ald(pml + (bb * 4 + 0) * 2 + 1), l1 = ald(pml + (bb * 4 + 1) * 2 + 1);
      float l2 = ald(pml + (bb * 4 + 2) * 2 + 1), l3 = ald(pml + (bb * 4 + 3) * 2 + 1);
      float M = fmaxf(fmaxf(m0, m1), fmaxf(m2, m3));
      float e0 = expf(m0 - M), e1 = expf(m1 - M), e2 = expf(m2 - M), e3 = expf(m3 - M);
      float L = l0 * e0 + l1 * e1 + l2 * e2 + l3 * e3;
      L = fmaxf(L, 1e-30f);
      for (int h = tid; h < 512; h += 256) {
        float hv = (ald(pac + (bb * 4 + 0) * 512 + h) * e0 +
                    ald(pac + (bb * 4 + 1) * 512 + h) * e1 +
                    ald(pac + (bb * 4 + 2) * 512 + h) * e2 +
                    ald(pac + (bb * 4 + 3) * 512 + h) * e3) / L;
        ast(aoT + h * 64 + bb, hv);
      }
      float bestA = -1.0f;
      int bestS = 0;
#pragma unroll
      for (int k = 0; k < 2; ++k) {
        int s = tid * 2 + k;
        float a = expf(ald(att + bb * 512 + s) - M) / L;
        out[(bb * 32 + t) * 512 + s] = a;
        if (a > bestA) { bestA = a; bestS = s; }
      }
      redA[tid] = bestA;
      redI[tid] = bestS;
      __syncthreads();
      for (int st = 128; st > 0; st >>= 1) {
        if (tid < st) {
          if (redA[tid + st] > redA[tid]) { redA[tid] = redA[tid + st]; redI[tid] = redI[tid + st]; }
        }
        __syncthreads();
      }
      int idx = redI[0];
      if (tid == 0) {
        ast(mask + bb * 512 + idx, 0.0f);
        out[1048576 + bb * 32 + t] = (float)idx;
      }
      int token = sent[idx * 64 + bb];
      ast(dinT + tid * 64 + bb, wget(embD, (long)token * 256 + tid, f32m));
    }
    ++bgen;
    fbar_arrive(ws, FLD_OFF, wg, bgen);
    fbar_wait(ws, FLD_OFF, 256, bgen);
    // ---- P5: h_new = tanh([hidden|h_t] @ Wout^T + bout) ----
    if (wg >= 160 && wg < 192) {
      float aH[4][8];
#pragma unroll
      for (int pf = 0; pf < 3; ++pf) ld8T(aoT, pf * 32 + q * 8, bA, aH[pf]);
      f32x4 acc = {0.f, 0.f, 0.f, 0.f};
#pragma unroll
      for (int kk = 0; kk < 32; ++kk) {
        if (kk + 3 < 32) ld8T(aoT, (kk + 3) * 32 + q * 8, bA, aH[(kk + 3) & 3]);
        acc = groupMMv(aH[kk & 3], B3 + (kk >> 3) * 12672,
                       ln15 * 264 + (kk & 7) * 32 + q * 8, acc);
      }
      const int d = (wg - 160) * 16 + ln15;
      float bb = wget(bout, d, f32m);
#pragma unroll
      for (int r = 0; r < 4; ++r)
        ast(hdT + d * 64 + (v * 16 + q * 4 + r), tanhf(acc[r] + bb));
    }
    ++bgen;
    fbar_arrive(ws, FLD_OFF, wg, bgen);
    // ---- g5 window: P1's dinT part for t+1 (dinT visible since g4) ----
    if (wg < 128 && t < 31) {
      float aD[4][8];
#pragma unroll
      for (int pf = 0; pf < 3; ++pf) ld8T(dinT, pf * 32 + q * 8, bA, aD[pf]);
      f32x4 accn = {0.f, 0.f, 0.f, 0.f};
#pragma unroll
      for (int ks = 0; ks < 8; ++ks) {
        if (ks + 3 < 8) ld8T(dinT, (ks + 3) * 32 + q * 8, bA, aD[(ks + 3) & 3]);
        accn = groupMMv(aD[ks & 3], B3, ln15 * 264 + ks * 32 + q * 8, accn);
      }
      acc1 = accn;
    }
    if (t < 31) fbar_wait(ws, FLD_OFF, 256, bgen);
  }
}

// =================== diagnostic ===================
__global__ void diag_kernel(char* ws, float* out, int wsMiB) {
  if (threadIdx.x == 0 && blockIdx.x == 0) {
    int f = *(int*)(ws + FLG_OFF);
    out[0] = (float)(wsMiB + 2000 * f);
  }
}

extern "C" void kernel_launch(void* const* d_in, const int* in_sizes, int n_in,
                              void* d_out, int out_size, void* d_ws, size_t ws_size,
                              hipStream_t stream) {
  (void)in_sizes; (void)n_in; (void)out_size;
  const int* sent = (const int*)d_in[0];
  const void* embE = d_in[1];
  const void* embD = d_in[2];
  const void* Wih = d_in[3];
  const void* Whh = d_in[4];
  const void* bih = d_in[5];
  const void* bhh = d_in[6];
  const void* din0 = d_in[7];
  const void* Wx = d_in[8];
  const void* bx = d_in[9];
  const void* Wh = d_in[10];
  const void* bh = d_in[11];
  const void* Wout = d_in[12];
  const void* bout = d_in[13];
  const void* Win = d_in[14];
  const void* bin = d_in[15];
  const void* Wctx = d_in[16];
  const void* bctx = d_in[17];
  const void* V = d_in[18];
  char* ws = (char*)d_ws;
  float* out = (float*)d_out;

  int tier;
  if (ws_size >= (size_t)NEED_T0) tier = 0;
  else if (ws_size >= (size_t)NEED_T1) tier = 1;
  else if (ws_size >= (size_t)NEED_T2) tier = 2;
  else tier = 3;

  prep_detect<<<dim3(1), dim3(256), 0, stream>>>(embE, ws);
  prep_init<<<dim3(64), dim3(256), 0, stream>>>(din0, ws);
  enc_pers<<<dim3(160), dim3(256), 0, stream>>>(sent, embE, Wih, Whh, bih, bhh,
                                                Wctx, bctx, ws, tier);
  dec_pers<<<dim3(256), dim3(256), 0, stream>>>(sent, embD, Wx, bx, Wh, bh, Wout, bout,
                                                Win, bin, V, ws, out, tier);
  if (tier >= 2)
    diag_kernel<<<dim3(1), dim3(64), 0, stream>>>(ws, out, (int)(ws_size >> 20));
}